// Round 1
// baseline (119866.577 us; speedup 1.0000x reference)
//
#include <hip/hip_runtime.h>
#include <hip/hip_cooperative_groups.h>

namespace cg = cooperative_groups;

#define BB 32
#define S_ENCC 200
#define TT 400
#define MMM 80
#define E2C 512
#define HHH 1024
#define IN0C 592      // MMM + E2C
#define KTOT 1616     // IN0C + HHH
#define NBLK 256
#define NTHR 256
#define IBUF (BB*KTOT)

__device__ __forceinline__ float sigmf(float x){ return 1.0f/(1.0f+expf(-x)); }

__device__ __forceinline__ float blockReduceSum(float v, float* red){
  int tid = threadIdx.x;
  red[tid]=v; __syncthreads();
  for (int s=NTHR/2; s>0; s>>=1){ if (tid<s) red[tid]+=red[tid+s]; __syncthreads(); }
  float r = red[0]; __syncthreads(); return r;
}
__device__ __forceinline__ float blockReduceMax(float v, float* red){
  int tid = threadIdx.x;
  red[tid]=v; __syncthreads();
  for (int s=NTHR/2; s>0; s>>=1){ if (tid<s) red[tid]=fmaxf(red[tid],red[tid+s]); __syncthreads(); }
  float r = red[0]; __syncthreads(); return r;
}

// Stage a [32 x L] chunk of the activation matrix into LDS (k-major, +1 pad),
// then accumulate 4 gate dot-products for this thread's (b,h).
template<int L>
__device__ __forceinline__ void gemm_chunk(float* sh,
    const float* __restrict__ src, int sstride, int k0,
    const float* __restrict__ W, int wstride, int kw0,
    int b, int h, float acc[4])
{
  __syncthreads();
  for (int idx = threadIdx.x; idx < 32*L; idx += NTHR) {
    int bbq = idx / L, kk = idx - bbq*L;
    sh[kk*33 + bbq] = src[bbq*sstride + k0 + kk];
  }
  __syncthreads();
  #pragma unroll 4
  for (int kk = 0; kk < L; kk += 4) {
    float x0 = sh[(kk+0)*33+b], x1 = sh[(kk+1)*33+b];
    float x2 = sh[(kk+2)*33+b], x3 = sh[(kk+3)*33+b];
    #pragma unroll
    for (int g = 0; g < 4; ++g) {
      const float4 w = *(const float4*)(W + (size_t)(g*HHH + h)*wstride + kw0 + kk);
      acc[g] = fmaf(w.x,x0, fmaf(w.y,x1, fmaf(w.z,x2, fmaf(w.w,x3, acc[g]))));
    }
  }
}

__global__ void __launch_bounds__(NTHR) decoder_kernel(
    const float* __restrict__ enc, const float* __restrict__ audio,
    const float* __restrict__ Wih0, const float* __restrict__ Whh0,
    const float* __restrict__ bih0, const float* __restrict__ bhh0,
    const float* __restrict__ Wih1, const float* __restrict__ Whh1,
    const float* __restrict__ bih1, const float* __restrict__ bhh1,
    const float* __restrict__ Wa, const float* __restrict__ ba,
    const float* __restrict__ Wfc, const float* __restrict__ bfc,
    float* __restrict__ out, float* __restrict__ ws)
{
  cg::grid_group grid = cg::this_grid();
  const int blk = blockIdx.x, tid = threadIdx.x;

  float* inp  = ws;                 // 2 * 32 * 1616 (double-buffered [x|ctx|h0] rows)
  float* c0   = ws + 2*IBUF;        // 32*1024
  float* h1   = c0 + BB*HHH;        // 32*1024
  float* c1   = h1 + BB*HHH;        // 32*1024
  float* esc  = c1 + BB*HHH;        // 32*200  (precomputed tanh(enc)@wa_e)
  float* G1p  = esc + BB*S_ENCC;    // 32*4096 (LSTM1 partial gates)

  __shared__ float sh[64*33];
  __shared__ float red[NTHR];
  __shared__ float smw[256];

  // ---- init: zero states, h0-part of inp buffer 0; precompute enc_score ----
  for (int i = blk*NTHR+tid; i < BB*HHH; i += NBLK*NTHR) {
    c0[i]=0.f; c1[i]=0.f; h1[i]=0.f;
    inp[(i>>10)*KTOT + IN0C + (i&1023)] = 0.f;
  }
  for (int row = blk; row < BB*S_ENCC; row += NBLK) {
    const float* ep = enc + (size_t)row*E2C;
    float p=0.f;
    for (int e=tid; e<E2C; e+=NTHR) p += tanhf(ep[e])*Wa[HHH+e];
    p = blockReduceSum(p, red);
    if (tid==0) esc[row]=p;
  }
  grid.sync();

  int cur = 0;
  for (int t = 0; t < TT; ++t) {
    float* inpc = inp + cur*IBUF;
    float* inpn = inp + (1-cur)*IBUF;

    // ---- Phase A: attention -> ctx (blocks 0..31); pred[t-1] (blocks 32..63)
    if (blk < BB) {
      int b = blk;
      for (int m = tid; m < MMM; m += NTHR)
        inpc[b*KTOT + m] = audio[((size_t)b*TT + t)*MMM + m];
      if (t == 0) {
        for (int e = tid; e < E2C; e += NTHR) {
          float s = 0.f;
          const float* ep = enc + ((size_t)b*S_ENCC)*E2C + e;
          for (int si=0; si<S_ENCC; ++si) s += ep[(size_t)si*E2C];
          inpc[b*KTOT + MMM + e] = s * (1.0f/S_ENCC);
        }
      } else {
        const float* h1b = h1 + b*HHH;
        float p = 0.f;
        for (int hh = tid; hh < HHH; hh += NTHR) p += tanhf(h1b[hh]) * Wa[hh];
        float sdot = blockReduceSum(p, red) + ba[0];
        float sc = (tid < S_ENCC) ? (esc[b*S_ENCC+tid] + sdot) : -1e30f;
        float mx = blockReduceMax(sc, red);
        float ex = (tid < S_ENCC) ? expf(sc - mx) : 0.f;
        float den = blockReduceSum(ex, red);
        if (tid < S_ENCC) smw[tid] = ex / den;
        __syncthreads();
        for (int e = tid; e < E2C; e += NTHR) {
          float a = 0.f;
          const float* ep = enc + ((size_t)b*S_ENCC)*E2C + e;
          for (int si=0; si<S_ENCC; ++si) a = fmaf(smw[si], ep[(size_t)si*E2C], a);
          inpc[b*KTOT + MMM + e] = a;
        }
        __syncthreads();
      }
    } else if (blk >= BB && blk < 2*BB && t > 0) {
      int b = blk - BB;
      const float* h1b = h1 + b*HHH;
      if (tid < MMM) {
        const float* wr = Wfc + tid*HHH;
        float a = 0.f;
        for (int k=0;k<HHH;++k) a = fmaf(h1b[k], wr[k], a);
        out[((size_t)b*TT + (t-1))*MMM + tid] = a + bfc[tid];
      }
    }
    grid.sync();

    // ---- Phase B: LSTM0 full (blocks 0..127) || LSTM1 h1@Whh1 partial (128..255)
    {
      int b = tid & 31, hl = tid >> 5;
      if (blk < 128) {
        int h = blk*8 + hl;
        float acc[4] = {0.f,0.f,0.f,0.f};
        for (int c=0;c<9;++c)  gemm_chunk<64>(sh, inpc, KTOT, c*64, Wih0, IN0C, c*64, b,h,acc);
        gemm_chunk<16>(sh, inpc, KTOT, 576, Wih0, IN0C, 576, b,h,acc);
        for (int c=0;c<16;++c) gemm_chunk<64>(sh, inpc+IN0C, KTOT, c*64, Whh0, HHH, c*64, b,h,acc);
        float gi = acc[0] + bih0[h]        + bhh0[h];
        float gf = acc[1] + bih0[HHH+h]    + bhh0[HHH+h];
        float gg = acc[2] + bih0[2*HHH+h]  + bhh0[2*HHH+h];
        float go = acc[3] + bih0[3*HHH+h]  + bhh0[3*HHH+h];
        float cn = sigmf(gf)*c0[b*HHH+h] + sigmf(gi)*tanhf(gg);
        c0[b*HHH+h] = cn;
        inpn[b*KTOT + IN0C + h] = sigmf(go)*tanhf(cn);
      } else {
        int h = (blk-128)*8 + hl;
        float acc[4] = {0.f,0.f,0.f,0.f};
        for (int c=0;c<16;++c) gemm_chunk<64>(sh, h1, HHH, c*64, Whh1, HHH, c*64, b,h,acc);
        #pragma unroll
        for (int g=0; g<4; ++g)
          G1p[b*4096 + g*HHH + h] = acc[g] + bih1[g*HHH+h] + bhh1[g*HHH+h];
      }
    }
    grid.sync();

    // ---- Phase C: LSTM1 h0'@Wih1 + gates (blocks 0..127)
    if (blk < 128) {
      int b = tid & 31, h = blk*8 + (tid>>5);
      float acc[4] = {0.f,0.f,0.f,0.f};
      for (int c=0;c<16;++c) gemm_chunk<64>(sh, inpn+IN0C, KTOT, c*64, Wih1, HHH, c*64, b,h,acc);
      float gi = acc[0] + G1p[b*4096 + h];
      float gf = acc[1] + G1p[b*4096 + HHH + h];
      float gg = acc[2] + G1p[b*4096 + 2*HHH + h];
      float go = acc[3] + G1p[b*4096 + 3*HHH + h];
      float cn = sigmf(gf)*c1[b*HHH+h] + sigmf(gi)*tanhf(gg);
      c1[b*HHH+h] = cn;
      h1[b*HHH+h] = sigmf(go)*tanhf(cn);
    }
    grid.sync();
    cur ^= 1;
  }

  // ---- final pred for t = TT-1 ----
  if (blk >= BB && blk < 2*BB) {
    int b = blk - BB;
    const float* h1b = h1 + b*HHH;
    if (tid < MMM) {
      const float* wr = Wfc + tid*HHH;
      float a = 0.f;
      for (int k=0;k<HHH;++k) a = fmaf(h1b[k], wr[k], a);
      out[((size_t)b*TT + (TT-1))*MMM + tid] = a + bfc[tid];
    }
  }
}

extern "C" void kernel_launch(void* const* d_in, const int* in_sizes, int n_in,
                              void* d_out, int out_size, void* d_ws, size_t ws_size,
                              hipStream_t stream) {
  const float* enc  = (const float*)d_in[0];
  const float* audio= (const float*)d_in[1];
  const float* Wih0 = (const float*)d_in[2];
  const float* Whh0 = (const float*)d_in[3];
  const float* bih0 = (const float*)d_in[4];
  const float* bhh0 = (const float*)d_in[5];
  const float* Wih1 = (const float*)d_in[6];
  const float* Whh1 = (const float*)d_in[7];
  const float* bih1 = (const float*)d_in[8];
  const float* bhh1 = (const float*)d_in[9];
  const float* Wa   = (const float*)d_in[10];
  const float* ba   = (const float*)d_in[11];
  const float* Wfc  = (const float*)d_in[12];
  const float* bfc  = (const float*)d_in[13];
  float* out = (float*)d_out;
  float* ws  = (float*)d_ws;
  void* args[] = { &enc,&audio,&Wih0,&Whh0,&bih0,&bhh0,&Wih1,&Whh1,&bih1,&bhh1,
                   &Wa,&ba,&Wfc,&bfc,&out,&ws };
  hipLaunchCooperativeKernel((const void*)decoder_kernel, dim3(NBLK), dim3(NTHR),
                             args, 0, stream);
}

// Round 2
// 91452.588 us; speedup vs baseline: 1.3107x; 1.3107x over previous
//
#include <hip/hip_runtime.h>
#include <hip/hip_cooperative_groups.h>

namespace cg = cooperative_groups;

#define BB 32
#define SE 200
#define TT 400
#define MM 80
#define EE 512
#define HH 1024
#define IN0 592
#define KT 1616        // IN0 + HH
#define NG 4096        // 4*HH
#define NBLK 256
#define NTHR 512
#define IBUF (BB*KT)

#define DOT(a,xv,wv) a = fmaf((xv).x,(wv).x, fmaf((xv).y,(wv).y, fmaf((xv).z,(wv).z, fmaf((xv).w,(wv).w,(a)))))

__device__ __forceinline__ float sigmf(float x){ return 1.0f/(1.0f+expf(-x)); }

__device__ __forceinline__ float blockReduceSum(float v, float* red){
  int tid = threadIdx.x;
  red[tid]=v; __syncthreads();
  for (int s=NTHR/2; s>0; s>>=1){ if (tid<s) red[tid]+=red[tid+s]; __syncthreads(); }
  float r = red[0]; __syncthreads(); return r;
}
__device__ __forceinline__ float blockReduceMax(float v, float* red){
  int tid = threadIdx.x;
  red[tid]=v; __syncthreads();
  for (int s=NTHR/2; s>0; s>>=1){ if (tid<s) red[tid]=fmaxf(red[tid],red[tid+s]); __syncthreads(); }
  float r = red[0]; __syncthreads(); return r;
}

// Stage X[32][len] (k-slice) into LDS, b-major, row stride = len+4 (bank-safe).
__device__ __forceinline__ void stage_x(float* Xs, int xstr, int len,
    const float* __restrict__ src, int sstride, int k0)
{
  const int nq = len >> 2;
  for (int i = threadIdx.x; i < BB*nq; i += NTHR) {
    int b = i / nq, q = i - b*nq;
    *(float4*)&Xs[b*xstr + q*4] = *(const float4*)&src[(size_t)b*sstride + k0 + q*4];
  }
}

// Each thread: acc tile rb=4 (b = bgrp+8j) x rn=4 (n = n0+ngrp+64j) over k-slice in LDS.
// Writes fp32 partials to Gout[(srow+b)*NG + n].
__device__ __forceinline__ void gemm_core(const float* Xs, int xstr, int len,
    const float* __restrict__ W, int wK, int wk0, int n0,
    float* __restrict__ Gout, int srow)
{
  const int tid = threadIdx.x;
  const int bgrp = tid & 7, ngrp = tid >> 3;
  float acc[4][4] = {{0.f,0.f,0.f,0.f},{0.f,0.f,0.f,0.f},{0.f,0.f,0.f,0.f},{0.f,0.f,0.f,0.f}};
  const float* wp0 = W + (size_t)(n0 + ngrp      )*wK + wk0;
  const float* wp1 = W + (size_t)(n0 + ngrp +  64)*wK + wk0;
  const float* wp2 = W + (size_t)(n0 + ngrp + 128)*wK + wk0;
  const float* wp3 = W + (size_t)(n0 + ngrp + 192)*wK + wk0;
  const float* xp0 = Xs + (bgrp     )*xstr;
  const float* xp1 = Xs + (bgrp +  8)*xstr;
  const float* xp2 = Xs + (bgrp + 16)*xstr;
  const float* xp3 = Xs + (bgrp + 24)*xstr;
  for (int kk = 0; kk < len; kk += 4) {
    float4 w0 = *(const float4*)(wp0 + kk);
    float4 w1 = *(const float4*)(wp1 + kk);
    float4 w2 = *(const float4*)(wp2 + kk);
    float4 w3 = *(const float4*)(wp3 + kk);
    float4 x0 = *(const float4*)(xp0 + kk);
    float4 x1 = *(const float4*)(xp1 + kk);
    float4 x2 = *(const float4*)(xp2 + kk);
    float4 x3 = *(const float4*)(xp3 + kk);
    DOT(acc[0][0],x0,w0); DOT(acc[0][1],x0,w1); DOT(acc[0][2],x0,w2); DOT(acc[0][3],x0,w3);
    DOT(acc[1][0],x1,w0); DOT(acc[1][1],x1,w1); DOT(acc[1][2],x1,w2); DOT(acc[1][3],x1,w3);
    DOT(acc[2][0],x2,w0); DOT(acc[2][1],x2,w1); DOT(acc[2][2],x2,w2); DOT(acc[2][3],x2,w3);
    DOT(acc[3][0],x3,w0); DOT(acc[3][1],x3,w1); DOT(acc[3][2],x3,w2); DOT(acc[3][3],x3,w3);
  }
  #pragma unroll
  for (int jb=0;jb<4;++jb){
    int b = bgrp + 8*jb;
    #pragma unroll
    for (int jn=0;jn<4;++jn){
      int n = n0 + ngrp + 64*jn;
      Gout[(size_t)(srow + b)*NG + n] = acc[jb][jn];
    }
  }
}

// LSTM1 gate reduce: sum 8 slices of Gp + 8 of Gc + biases, for (b, j).
__device__ __forceinline__ void gates1(const float* __restrict__ Gp, const float* __restrict__ Gc,
    const float* __restrict__ ba_, const float* __restrict__ bb_, int b, int j, float g[4])
{
  #pragma unroll
  for (int gg=0; gg<4; ++gg){
    int n = gg*HH + j;
    float v = ba_[n] + bb_[n];
    #pragma unroll
    for (int s=0;s<8;++s) v += Gp[(size_t)(s*BB + b)*NG + n];
    #pragma unroll
    for (int s=0;s<8;++s) v += Gc[(size_t)(s*BB + b)*NG + n];
    g[gg]=v;
  }
}

__global__ void __launch_bounds__(NTHR, 2) decoder_kernel(
    const float* __restrict__ enc, const float* __restrict__ audio,
    const float* __restrict__ Wih0, const float* __restrict__ Whh0,
    const float* __restrict__ bih0, const float* __restrict__ bhh0,
    const float* __restrict__ Wih1, const float* __restrict__ Whh1,
    const float* __restrict__ bih1, const float* __restrict__ bhh1,
    const float* __restrict__ Wa, const float* __restrict__ ba,
    const float* __restrict__ Wfc, const float* __restrict__ bfc,
    float* __restrict__ out, float* __restrict__ ws)
{
  cg::grid_group grid = cg::this_grid();
  const int blk = blockIdx.x, tid = threadIdx.x;

  __shared__ float smem[6784];   // X tiles / shH / shH4 / shC
  __shared__ float red[NTHR];
  __shared__ float smw[256];

  float* inp = ws;                    // 2*32*1616
  float* h1w = inp + 2*IBUF;          // 32*1024
  float* c0b = h1w + BB*HH;           // 2*32*1024
  float* c1b = c0b + 2*BB*HH;         // 2*32*1024
  float* esc = c1b + 2*BB*HH;         // 32*200
  float* G0  = esc + BB*SE;           // 8*32*4096
  float* G1p = G0  + 8*BB*NG;         // 8*32*4096
  float* G1c = G1p + 8*BB*NG;         // 8*32*4096

  // ---- prologue: zero states, precompute esc = tanh(enc)@wa_e ----
  for (int i = blk*NTHR + tid; i < BB*HH; i += NBLK*NTHR) {
    h1w[i]=0.f; c0b[i]=0.f; c0b[BB*HH+i]=0.f; c1b[i]=0.f; c1b[BB*HH+i]=0.f;
    inp[(i>>10)*KT + IN0 + (i&1023)] = 0.f;
  }
  for (int row = blk; row < BB*SE; row += NBLK) {
    float p = tanhf(enc[(size_t)row*EE + tid]) * Wa[HH + tid];  // EE == NTHR
    p = blockReduceSum(p, red);
    if (tid==0) esc[row]=p;
  }
  grid.sync();

  int cur = 0;
  for (int t = 0; t < TT; ++t) {
    float* inpc = inp + cur*IBUF;
    float* inpn = inp + (cur^1)*IBUF;
    const int cpar = t & 1;

    // ================= Phase A =================
    if (blk < 128) {
      // attention: b = blk>>2, e-part = blk&3. Also reduces LSTM1(t-1) -> h1,c1.
      const int b = blk >> 2, part = blk & 3;
      float* shH = smem;          // 1024
      float* shC = smem + 1024;   // 512
      if (t > 0) {
        for (int i = tid; i < HH; i += NTHR) {
          float g[4]; gates1(G1p, G1c, bih1, bhh1, b, i, g);
          float cold = c1b[cpar*BB*HH + b*HH + i];
          float cn = sigmf(g[1])*cold + sigmf(g[0])*tanhf(g[2]);
          float hn = sigmf(g[3])*tanhf(cn);
          shH[i] = hn;
          if (part == 0) { c1b[(cpar^1)*BB*HH + b*HH + i] = cn; h1w[b*HH + i] = hn; }
        }
        __syncthreads();
        float p = 0.f;
        for (int i = tid; i < HH; i += NTHR) p += tanhf(shH[i]) * Wa[i];
        float sdot = blockReduceSum(p, red) + ba[0];
        float sc = (tid < SE) ? esc[b*SE + tid] + sdot : -3.4e38f;
        float mx = blockReduceMax(sc, red);
        float ex = (tid < SE) ? expf(sc - mx) : 0.f;
        float den = blockReduceSum(ex, red);
        if (tid < SE) smw[tid] = ex / den;
      } else {
        if (tid < SE) smw[tid] = 1.0f/(float)SE;
      }
      __syncthreads();
      {
        int el = tid & 127, sg = tid >> 7;          // 4 s-groups of 50
        int e = part*128 + el;
        float a = 0.f;
        for (int s = sg*50; s < sg*50 + 50; ++s)
          a = fmaf(smw[s], enc[((size_t)b*SE + s)*EE + e], a);
        shC[sg*128 + el] = a;
        __syncthreads();
        if (tid < 128) inpc[(size_t)b*KT + MM + part*128 + tid] =
            shC[tid] + shC[128+tid] + shC[256+tid] + shC[384+tid];
      }
      if (part == 0 && tid < MM)
        inpc[(size_t)b*KT + tid] = audio[((size_t)b*TT + t)*MM + tid];
    } else if (blk < 136) {
      // FC: pred[t-1] for b = q*4..q*4+3 (recompute h1 from partials)
      const int q = blk - 128;
      if (t > 0) {
        float* shH4 = smem;  // 4096
        for (int i = tid; i < 4*HH; i += NTHR) {
          int j = i & (HH-1), bi = i >> 10, b = q*4 + bi;
          float g[4]; gates1(G1p, G1c, bih1, bhh1, b, j, g);
          float cold = c1b[cpar*BB*HH + b*HH + j];
          float cn = sigmf(g[1])*cold + sigmf(g[0])*tanhf(g[2]);
          shH4[i] = sigmf(g[3])*tanhf(cn);
        }
        __syncthreads();
        if (tid < 4*MM) {
          int bi = tid / MM, m = tid - bi*MM;
          const float* hr = shH4 + bi*HH;
          const float* wr = Wfc + (size_t)m*HH;
          float a = 0.f;
          for (int k = 0; k < HH; k += 4) {
            float4 xv = *(const float4*)(hr + k);
            float4 wv = *(const float4*)(wr + k);
            DOT(a, xv, wv);
          }
          out[((size_t)(q*4 + bi)*TT + (t-1))*MM + m] = a + bfc[m];
        }
      }
    }
    grid.sync();

    // ================= Phase B: LSTM0 gemm (blk<128) || h1@Whh1 (blk>=128) ====
    if (blk < 128) {
      int nt = blk >> 3, s = blk & 7;
      int len = (s < 3) ? (s==2 ? 176 : 208) : (s==7 ? 192 : 208);
      int k0  = (s < 3) ? s*208 : 592 + (s-3)*208;
      int xstr = len + 4;
      stage_x(smem, xstr, len, inpc, KT, k0);
      __syncthreads();
      const float* W = (s < 3) ? Wih0 : Whh0;
      int wK  = (s < 3) ? IN0 : HH;
      int wk0 = (s < 3) ? k0 : k0 - IN0;
      gemm_core(smem, xstr, len, W, wK, wk0, nt*256, G0, s*BB);
    } else {
      int nt = (blk-128) >> 3, s = blk & 7;
      stage_x(smem, 132, 128, h1w, HH, s*128);
      __syncthreads();
      gemm_core(smem, 132, 128, Whh1, HH, s*128, nt*256, G1p, s*BB);
    }
    grid.sync();

    // ================= Phase C: reduce LSTM0 -> h0'; gemm h0'@Wih1 ============
    if (blk < 128) {
      int nt = blk >> 3, ks = blk & 7;
      int kbase = ks*128;
      float* Xs = smem;  // stride 132
      for (int i = tid; i < BB*128; i += NTHR) {
        int j = i & 127, b = i >> 7;
        float g[4];
        #pragma unroll
        for (int gg=0; gg<4; ++gg){
          int n = gg*HH + kbase + j;
          float v = bih0[n] + bhh0[n];
          #pragma unroll
          for (int s8=0;s8<8;++s8) v += G0[(size_t)(s8*BB + b)*NG + n];
          g[gg]=v;
        }
        float cold = c0b[cpar*BB*HH + b*HH + kbase + j];
        float cn = sigmf(g[1])*cold + sigmf(g[0])*tanhf(g[2]);
        float hn = sigmf(g[3])*tanhf(cn);
        Xs[b*132 + j] = hn;
        if (nt == 0) {
          c0b[(cpar^1)*BB*HH + b*HH + kbase + j] = cn;
          inpn[(size_t)b*KT + IN0 + kbase + j] = hn;
        }
      }
      __syncthreads();
      gemm_core(Xs, 132, 128, Wih1, HH, kbase, nt*256, G1c, ks*BB);
    }
    grid.sync();
    cur ^= 1;
  }

  // ---- epilogue: pred[TT-1] ----
  if (blk >= 128 && blk < 136) {
    const int q = blk - 128;
    const int cpar = TT & 1;
    float* shH4 = smem;
    for (int i = tid; i < 4*HH; i += NTHR) {
      int j = i & (HH-1), bi = i >> 10, b = q*4 + bi;
      float g[4]; gates1(G1p, G1c, bih1, bhh1, b, j, g);
      float cold = c1b[cpar*BB*HH + b*HH + j];
      float cn = sigmf(g[1])*cold + sigmf(g[0])*tanhf(g[2]);
      shH4[i] = sigmf(g[3])*tanhf(cn);
    }
    __syncthreads();
    if (tid < 4*MM) {
      int bi = tid / MM, m = tid - bi*MM;
      const float* hr = shH4 + bi*HH;
      const float* wr = Wfc + (size_t)m*HH;
      float a = 0.f;
      for (int k = 0; k < HH; k += 4) {
        float4 xv = *(const float4*)(hr + k);
        float4 wv = *(const float4*)(wr + k);
        DOT(a, xv, wv);
      }
      out[((size_t)(q*4 + bi)*TT + (TT-1))*MM + m] = a + bfc[m];
    }
  }
}

extern "C" void kernel_launch(void* const* d_in, const int* in_sizes, int n_in,
                              void* d_out, int out_size, void* d_ws, size_t ws_size,
                              hipStream_t stream) {
  const float* enc  = (const float*)d_in[0];
  const float* audio= (const float*)d_in[1];
  const float* Wih0 = (const float*)d_in[2];
  const float* Whh0 = (const float*)d_in[3];
  const float* bih0 = (const float*)d_in[4];
  const float* bhh0 = (const float*)d_in[5];
  const float* Wih1 = (const float*)d_in[6];
  const float* Whh1 = (const float*)d_in[7];
  const float* bih1 = (const float*)d_in[8];
  const float* bhh1 = (const float*)d_in[9];
  const float* Wa   = (const float*)d_in[10];
  const float* ba   = (const float*)d_in[11];
  const float* Wfc  = (const float*)d_in[12];
  const float* bfc  = (const float*)d_in[13];
  float* out = (float*)d_out;
  float* ws  = (float*)d_ws;
  void* args[] = { &enc,&audio,&Wih0,&Whh0,&bih0,&bhh0,&Wih1,&Whh1,&bih1,&bhh1,
                   &Wa,&ba,&Wfc,&bfc,&out,&ws };
  hipLaunchCooperativeKernel((const void*)decoder_kernel, dim3(NBLK), dim3(NTHR),
                             args, 0, stream);
}

// Round 3
// 52736.481 us; speedup vs baseline: 2.2729x; 1.7341x over previous
//
#include <hip/hip_runtime.h>
#include <hip/hip_cooperative_groups.h>

namespace cg = cooperative_groups;

#define BBAT 32
#define SE 200
#define TT 400
#define MM 80
#define EE 512
#define HH 1024
#define IN0 592
#define KT 1616
#define NBLK 256
#define NTHR 512
#define IBUF (BBAT*KT)

// LDS layout (bytes)
#define W0_STR   1624              // 1616 + 8 pad (bf16 elems), rows 16B-aligned
#define W1_STR   1032              // 1024 + 8 pad
#define OFF_W0   0                 // 16*1624*2 = 51968
#define OFF_W1I  51968             // 16*1032*2 = 33024
#define OFF_W1H  84992
#define OFF_POOL 118016            // 8448 floats = 33792 B (dbuf X / Gred / attn scratch)
#define OFF_GS1P 151808            // 512 f32
#define OFF_GSUM 153856            // 512 f32
#define OFF_C0   155904            // 128 f32
#define OFF_C1   156416            // 128 f32
#define LDS_TOTAL 156928

__device__ __forceinline__ float sigmf(float x){ return 1.0f/(1.0f+expf(-x)); }

__device__ __forceinline__ unsigned short f2bf(float v){
  unsigned int u = __float_as_uint(v);
  u += 0x7fffu + ((u >> 16) & 1u);         // RNE; inputs are finite
  return (unsigned short)(u >> 16);
}

__device__ __forceinline__ float bsum(float v, float* red){
  #pragma unroll
  for (int o = 32; o; o >>= 1) v += __shfl_down(v, o);
  __syncthreads();
  if ((threadIdx.x & 63) == 0) red[threadIdx.x >> 6] = v;
  __syncthreads();
  float s = 0.f;
  #pragma unroll
  for (int w2 = 0; w2 < 8; ++w2) s += red[w2];
  return s;
}
__device__ __forceinline__ float bmax(float v, float* red){
  #pragma unroll
  for (int o = 32; o; o >>= 1) v = fmaxf(v, __shfl_down(v, o));
  __syncthreads();
  if ((threadIdx.x & 63) == 0) red[threadIdx.x >> 6] = v;
  __syncthreads();
  float s = -3.4e38f;
  #pragma unroll
  for (int w2 = 0; w2 < 8; ++w2) s = fmaxf(s, red[w2]);
  return s;
}

// Block GEMM: out[32b x 16r] = X[32 x K] * W^T (W rows in LDS bf16).
// thread: bq=tid&7, rq=(tid>>3)&3, ks=tid>>5 (16 k-slices of 8 within each 128-chunk).
// Double-buffered X staging in pool (2 x 32 x 132 f32), then Gred[16][512] reduce.
__device__ __forceinline__ void block_gemm(const unsigned short* __restrict__ Wl, const int wstr,
    const float* __restrict__ Xg, const int xstr, const int K,
    float* __restrict__ pool, float* __restrict__ gout)
{
  const int tid = threadIdx.x;
  const int bq = tid & 7, rq = (tid >> 3) & 3, ks = tid >> 5;
  float acc[4][4] = {{0,0,0,0},{0,0,0,0},{0,0,0,0},{0,0,0,0}};
  const int nch = (K + 127) >> 7;

  { // stage chunk 0
    int klen = K < 128 ? K : 128, nq = klen >> 2;
    for (int i = tid; i < 32*nq; i += NTHR) {
      int b, q;
      if (nq == 32) { b = i >> 5; q = i & 31; } else { b = i / nq; q = i - b*nq; }
      *(float4*)(pool + b*132 + (q<<2)) = *(const float4*)(Xg + (size_t)b*xstr + (q<<2));
    }
  }
  __syncthreads();

  for (int c = 0; c < nch; ++c) {
    const float* xc = pool + ((c & 1) ? 4224 : 0);
    const int klen = (K - (c<<7)) < 128 ? (K - (c<<7)) : 128;
    if (c + 1 < nch) {   // stage next chunk into other half
      float* xn = pool + (((c+1) & 1) ? 4224 : 0);
      const int k0 = (c+1) << 7;
      const int kl2 = (K - k0) < 128 ? (K - k0) : 128, nq = kl2 >> 2;
      for (int i = tid; i < 32*nq; i += NTHR) {
        int b, q;
        if (nq == 32) { b = i >> 5; q = i & 31; } else { b = i / nq; q = i - b*nq; }
        *(float4*)(xn + b*132 + (q<<2)) = *(const float4*)(Xg + (size_t)b*xstr + k0 + (q<<2));
      }
    }
    if ((ks << 3) < klen) {
      const int kk0 = ks << 3;
      float4 xa[4], xb4[4];
      #pragma unroll
      for (int bi = 0; bi < 4; ++bi) {
        const float4* xp = (const float4*)(xc + (bq + (bi<<3))*132 + kk0);
        xa[bi] = xp[0]; xb4[bi] = xp[1];
      }
      #pragma unroll
      for (int ri = 0; ri < 4; ++ri) {
        const int r = rq + (ri << 2);
        const uint4 wv = *(const uint4*)(Wl + r*wstr + (c<<7) + kk0);
        const unsigned int wu[4] = {wv.x, wv.y, wv.z, wv.w};
        #pragma unroll
        for (int u = 0; u < 4; ++u) {
          const float wlo = __uint_as_float(wu[u] << 16);
          const float whi = __uint_as_float(wu[u] & 0xffff0000u);
          #pragma unroll
          for (int bi = 0; bi < 4; ++bi) {
            const float* xs = (u < 2) ? (const float*)&xa[bi] : (const float*)&xb4[bi];
            const float xlo = xs[(u & 1) ? 2 : 0];
            const float xhi = xs[(u & 1) ? 3 : 1];
            acc[bi][ri] = fmaf(wlo, xlo, acc[bi][ri]);
            acc[bi][ri] = fmaf(whi, xhi, acc[bi][ri]);
          }
        }
      }
    }
    __syncthreads();
  }
  // write k-partials (Gred = pool[16][512]) and reduce
  #pragma unroll
  for (int bi = 0; bi < 4; ++bi)
    #pragma unroll
    for (int ri = 0; ri < 4; ++ri)
      pool[(ks << 9) + (rq + (ri<<2))*32 + bq + (bi<<3)] = acc[bi][ri];
  __syncthreads();
  float s = 0.f;
  #pragma unroll
  for (int k2 = 0; k2 < 16; ++k2) s += pool[(k2 << 9) + tid];
  gout[tid] = s;   // o = r*32 + b ; caller syncs before reading
}

__global__ void __launch_bounds__(NTHR) decoder_kernel(
    const float* __restrict__ enc, const float* __restrict__ audio,
    const float* __restrict__ Wih0, const float* __restrict__ Whh0,
    const float* __restrict__ bih0, const float* __restrict__ bhh0,
    const float* __restrict__ Wih1, const float* __restrict__ Whh1,
    const float* __restrict__ bih1, const float* __restrict__ bhh1,
    const float* __restrict__ Wa, const float* __restrict__ ba,
    const float* __restrict__ Wfc, const float* __restrict__ bfc,
    float* __restrict__ out, float* __restrict__ ws)
{
  cg::grid_group grid = cg::this_grid();
  extern __shared__ char lds[];
  unsigned short* W0  = (unsigned short*)(lds + OFF_W0);
  unsigned short* W1I = (unsigned short*)(lds + OFF_W1I);
  unsigned short* W1H = (unsigned short*)(lds + OFF_W1H);
  float* pool = (float*)(lds + OFF_POOL);
  float* Gs1p = (float*)(lds + OFF_GS1P);
  float* Gsum = (float*)(lds + OFF_GSUM);
  float* c0l  = (float*)(lds + OFF_C0);
  float* c1l  = (float*)(lds + OFF_C1);

  const int blk = blockIdx.x, tid = threadIdx.x;
  const int j = blk;                      // owns h-indices [4j, 4j+4)
  float* inp = ws;                        // 2 x [32][1616]
  float* h1g = ws + 2*IBUF;               // [32][1024]
  float* esc = h1g + BBAT*HH;             // [32][200]

  // ---- prologue: weights -> LDS bf16 (row r = p*4+g <-> gate-row n = g*1024 + 4j+p) ----
  for (int i = tid; i < 16*W0_STR; i += NTHR) {
    int r = i / W0_STR, k = i - r*W0_STR;
    int g = r & 3, p = r >> 2, n = g*HH + 4*j + p;
    float v = 0.f;
    if (k < IN0) v = Wih0[(size_t)n*IN0 + k];
    else if (k < KT) v = Whh0[(size_t)n*HH + (k - IN0)];
    W0[i] = f2bf(v);
  }
  for (int i = tid; i < 16*W1_STR; i += NTHR) {
    int r = i / W1_STR, k = i - r*W1_STR;
    int g = r & 3, p = r >> 2, n = g*HH + 4*j + p;
    float vi = (k < HH) ? Wih1[(size_t)n*HH + k] : 0.f;
    float vh = (k < HH) ? Whh1[(size_t)n*HH + k] : 0.f;
    W1I[i] = f2bf(vi);
    W1H[i] = f2bf(vh);
  }
  if (tid < 128) { c0l[tid] = 0.f; c1l[tid] = 0.f; }
  for (int i = blk*NTHR + tid; i < BBAT*HH; i += NBLK*NTHR) {
    h1g[i] = 0.f;
    inp[(i >> 10)*KT + IN0 + (i & 1023)] = 0.f;
  }
  { // esc[b][s] = tanh(enc[b,s,:]) . wa_e
    float* redp = pool + 256;
    for (int row = blk; row < BBAT*SE; row += NBLK) {
      float pp = tanhf(enc[(size_t)row*EE + tid]) * Wa[HH + tid];   // EE == NTHR
      pp = bsum(pp, redp);
      if (tid == 0) esc[row] = pp;
    }
  }
  grid.sync();

  int cur = 0;
  for (int t = 0; t < TT; ++t) {
    float* inpA = inp + cur*IBUF;
    float* inpN = inp + (cur^1)*IBUF;

    // ================= Phase A: Whh1 partial; attention -> ctx; FC pred(t-1) ====
    block_gemm(W1H, W1_STR, h1g, HH, HH, pool, Gs1p);
    __syncthreads();
    {
      const int b = blk & 31, esl = blk >> 5;
      float* smw  = pool;          // [256]
      float* redp = pool + 256;    // [64]
      float* shC  = pool + 320;    // [512]
      if (t > 0) {
        float pp = 0.f;
        for (int i2 = tid; i2 < HH; i2 += NTHR) pp += tanhf(h1g[b*HH + i2]) * Wa[i2];
        float sdot = bsum(pp, redp) + ba[0];
        float sc = (tid < SE) ? esc[b*SE + tid] + sdot : -3.4e38f;
        float mx = bmax(sc, redp);
        float ex = (tid < SE) ? expf(sc - mx) : 0.f;
        float den = bsum(ex, redp);
        if (tid < SE) smw[tid] = ex / den;
      } else {
        if (tid < SE) smw[tid] = 1.0f / (float)SE;
      }
      __syncthreads();
      const int sg = tid >> 6, el = tid & 63;
      const int e = esl*64 + el;
      float a = 0.f;
      for (int s2 = sg*25; s2 < sg*25 + 25; ++s2)
        a = fmaf(smw[s2], enc[((size_t)b*SE + s2)*EE + e], a);
      shC[sg*64 + el] = a;
      __syncthreads();
      if (tid < 64) {
        float r8 = 0.f;
        #pragma unroll
        for (int s3 = 0; s3 < 8; ++s3) r8 += shC[s3*64 + tid];
        inpA[(size_t)b*KT + MM + esl*64 + tid] = r8;
      }
      if (esl == 0 && tid < MM)
        inpA[(size_t)b*KT + tid] = audio[((size_t)b*TT + t)*MM + tid];
    }
    if (t > 0) { // FC pred for t-1: 10 (b,m) pairs per block
      const int w = tid >> 6, lane = tid & 63;
      for (int u = w; u < 10; u += 8) {
        int idx = j*10 + u;
        int b = idx / MM, m = idx - b*MM;
        float pp = 0.f;
        #pragma unroll
        for (int cq = 0; cq < 4; ++cq) {
          float4 hv = *(const float4*)(h1g + (size_t)b*HH + cq*256 + lane*4);
          float4 wv = *(const float4*)(Wfc + (size_t)m*HH + cq*256 + lane*4);
          pp = fmaf(hv.x,wv.x, fmaf(hv.y,wv.y, fmaf(hv.z,wv.z, fmaf(hv.w,wv.w, pp))));
        }
        #pragma unroll
        for (int o2 = 32; o2; o2 >>= 1) pp += __shfl_down(pp, o2);
        if (lane == 0) out[((size_t)b*TT + (t-1))*MM + m] = pp + bfc[m];
      }
    }
    grid.sync();

    // ================= Phase B: LSTM0 =================
    block_gemm(W0, W0_STR, inpA, KT, KT, pool, Gsum);
    __syncthreads();
    if (tid < 128) {
      const int b = tid & 31, p = tid >> 5;
      float g[4];
      #pragma unroll
      for (int gg = 0; gg < 4; ++gg) {
        int n = gg*HH + 4*j + p;
        g[gg] = Gsum[(p*4 + gg)*32 + b] + bih0[n] + bhh0[n];
      }
      float cn = sigmf(g[1]) * c0l[p*32 + b] + sigmf(g[0]) * tanhf(g[2]);
      c0l[p*32 + b] = cn;
      inpN[(size_t)b*KT + IN0 + 4*j + p] = sigmf(g[3]) * tanhf(cn);
    }
    grid.sync();

    // ================= Phase C: LSTM1 =================
    block_gemm(W1I, W1_STR, inpN + IN0, KT, HH, pool, Gsum);
    __syncthreads();
    if (tid < 128) {
      const int b = tid & 31, p = tid >> 5;
      float g[4];
      #pragma unroll
      for (int gg = 0; gg < 4; ++gg) {
        int n = gg*HH + 4*j + p;
        g[gg] = Gsum[(p*4 + gg)*32 + b] + Gs1p[(p*4 + gg)*32 + b] + bih1[n] + bhh1[n];
      }
      float cn = sigmf(g[1]) * c1l[p*32 + b] + sigmf(g[0]) * tanhf(g[2]);
      c1l[p*32 + b] = cn;
      h1g[(size_t)b*HH + 4*j + p] = sigmf(g[3]) * tanhf(cn);
    }
    grid.sync();
    cur ^= 1;
  }

  // ---- epilogue: FC pred for t = TT-1 ----
  {
    const int w = tid >> 6, lane = tid & 63;
    for (int u = w; u < 10; u += 8) {
      int idx = j*10 + u;
      int b = idx / MM, m = idx - b*MM;
      float pp = 0.f;
      #pragma unroll
      for (int cq = 0; cq < 4; ++cq) {
        float4 hv = *(const float4*)(h1g + (size_t)b*HH + cq*256 + lane*4);
        float4 wv = *(const float4*)(Wfc + (size_t)m*HH + cq*256 + lane*4);
        pp = fmaf(hv.x,wv.x, fmaf(hv.y,wv.y, fmaf(hv.z,wv.z, fmaf(hv.w,wv.w, pp))));
      }
      #pragma unroll
      for (int o2 = 32; o2; o2 >>= 1) pp += __shfl_down(pp, o2);
      if (lane == 0) out[((size_t)b*TT + (TT-1))*MM + m] = pp + bfc[m];
    }
  }
}

extern "C" void kernel_launch(void* const* d_in, const int* in_sizes, int n_in,
                              void* d_out, int out_size, void* d_ws, size_t ws_size,
                              hipStream_t stream) {
  const float* enc  = (const float*)d_in[0];
  const float* audio= (const float*)d_in[1];
  const float* Wih0 = (const float*)d_in[2];
  const float* Whh0 = (const float*)d_in[3];
  const float* bih0 = (const float*)d_in[4];
  const float* bhh0 = (const float*)d_in[5];
  const float* Wih1 = (const float*)d_in[6];
  const float* Whh1 = (const float*)d_in[7];
  const float* bih1 = (const float*)d_in[8];
  const float* bhh1 = (const float*)d_in[9];
  const float* Wa   = (const float*)d_in[10];
  const float* ba   = (const float*)d_in[11];
  const float* Wfc  = (const float*)d_in[12];
  const float* bfc  = (const float*)d_in[13];
  float* out = (float*)d_out;
  float* ws  = (float*)d_ws;

  static int lds_set = 0;
  (void)hipFuncSetAttribute((const void*)decoder_kernel,
                            hipFuncAttributeMaxDynamicSharedMemorySize, LDS_TOTAL);
  (void)lds_set;

  void* args[] = { &enc,&audio,&Wih0,&Whh0,&bih0,&bhh0,&Wih1,&Whh1,&bih1,&bhh1,
                   &Wa,&ba,&Wfc,&bfc,&out,&ws };
  hipLaunchCooperativeKernel((const void*)decoder_kernel, dim3(NBLK), dim3(NTHR),
                             args, LDS_TOTAL, stream);
}

// Round 4
// 41028.448 us; speedup vs baseline: 2.9215x; 1.2854x over previous
//
#include <hip/hip_runtime.h>
#include <hip/hip_cooperative_groups.h>

namespace cg = cooperative_groups;

#define BBAT 32
#define SE 200
#define TT 400
#define MM 80
#define EE 512
#define HH 1024
#define IN0 592
#define KT 1616
#define XSTR 1640      // inp row stride in bf16 elems (3280B: 16B-aligned, !=0 mod 32 words)
#define W1STR 1032
#define NBLK 256
#define NTHR 512

typedef __attribute__((ext_vector_type(4))) float f32x4;
typedef __attribute__((ext_vector_type(8))) short s16x8;

// LDS offsets (bytes)
#define OFF_W0    0          // 16*1640*2 = 52480
#define OFF_W1I   52480      // 16*1032*2 = 33024
#define OFF_W1H   85504      // 33024
#define OFF_GRED  118528     // 8*512 f32 = 16384
#define OFF_GSUM  134912     // 512 f32
#define OFF_GS1P  136960     // 512 f32
#define OFF_C0    139008     // 128 f32
#define OFF_C1    139520     // 128 f32
#define OFF_APOOL 140032     // smw 256 + red 64 + shC 512 = 832 f32
#define LDS_TOTAL 143360

__device__ __forceinline__ float sigmf(float x){ return 1.0f/(1.0f+expf(-x)); }

__device__ __forceinline__ unsigned short f2bf(float v){
  unsigned int u = __float_as_uint(v);
  u += 0x7fffu + ((u >> 16) & 1u);
  return (unsigned short)(u >> 16);
}

__device__ __forceinline__ float bsum(float v, float* red){
  #pragma unroll
  for (int o = 32; o; o >>= 1) v += __shfl_down(v, o);
  __syncthreads();
  if ((threadIdx.x & 63) == 0) red[threadIdx.x >> 6] = v;
  __syncthreads();
  float s = 0.f;
  #pragma unroll
  for (int w2 = 0; w2 < 8; ++w2) s += red[w2];
  return s;
}
__device__ __forceinline__ float bmax(float v, float* red){
  #pragma unroll
  for (int o = 32; o; o >>= 1) v = fmaxf(v, __shfl_down(v, o));
  __syncthreads();
  if ((threadIdx.x & 63) == 0) red[threadIdx.x >> 6] = v;
  __syncthreads();
  float s = -3.4e38f;
  #pragma unroll
  for (int w2 = 0; w2 < 8; ++w2) s = fmaxf(s, red[w2]);
  return s;
}

// out[32b x 16r] = X(bf16 global)[32 x 32*NCH] @ W(bf16 LDS)[16 x 32*NCH]^T
// Wave w handles chunks c == w (mod 8); partials reduced via Gred.
// gout[b*16 + r]; caller must __syncthreads() before reading gout.
template<int NCH>
__device__ __forceinline__ void gemm_mfma(
    const unsigned short* __restrict__ Wl, const int wstr,
    const unsigned short* __restrict__ Xg, const int xstr,
    float* __restrict__ Gred, float* __restrict__ gout)
{
  const int tid = threadIdx.x;
  const int w = tid >> 6, lane = tid & 63;
  const int row = lane & 15, kg = lane >> 4;
  f32x4 acc0 = {0.f,0.f,0.f,0.f}, acc1 = {0.f,0.f,0.f,0.f};
  const unsigned short* xp0 = Xg + (size_t)row * xstr + (kg << 3);
  const unsigned short* xp1 = xp0 + (size_t)16 * xstr;
  const unsigned short* wp  = Wl + row * wstr + (kg << 3);
  constexpr int NI = (NCH + 7) >> 3;
  #pragma unroll
  for (int i = 0; i < NI; ++i) {
    const int c = (i << 3) + w;
    if ((NCH & 7) == 0 || c < NCH) {
      s16x8 a0 = *(const s16x8*)(xp0 + (c << 5));
      s16x8 a1 = *(const s16x8*)(xp1 + (c << 5));
      s16x8 bw = *(const s16x8*)(wp  + (c << 5));
      acc0 = __builtin_amdgcn_mfma_f32_16x16x32_bf16(a0, bw, acc0, 0, 0, 0);
      acc1 = __builtin_amdgcn_mfma_f32_16x16x32_bf16(a1, bw, acc1, 0, 0, 0);
    }
  }
  float* gw = Gred + (w << 9) + row;
  #pragma unroll
  for (int v = 0; v < 4; ++v) {
    gw[((kg << 2) + v) << 4]        = acc0[v];
    gw[((kg << 2) + v + 16) << 4]   = acc1[v];
  }
  __syncthreads();
  float s = 0.f;
  #pragma unroll
  for (int w8 = 0; w8 < 8; ++w8) s += Gred[(w8 << 9) + tid];
  gout[tid] = s;
}

__global__ void __launch_bounds__(NTHR) decoder_kernel(
    const float* __restrict__ enc, const float* __restrict__ audio,
    const float* __restrict__ Wih0, const float* __restrict__ Whh0,
    const float* __restrict__ bih0, const float* __restrict__ bhh0,
    const float* __restrict__ Wih1, const float* __restrict__ Whh1,
    const float* __restrict__ bih1, const float* __restrict__ bhh1,
    const float* __restrict__ Wa, const float* __restrict__ ba,
    const float* __restrict__ Wfc, const float* __restrict__ bfc,
    float* __restrict__ out, float* __restrict__ ws)
{
  cg::grid_group grid = cg::this_grid();
  extern __shared__ char lds[];
  unsigned short* W0  = (unsigned short*)(lds + OFF_W0);
  unsigned short* W1I = (unsigned short*)(lds + OFF_W1I);
  unsigned short* W1H = (unsigned short*)(lds + OFF_W1H);
  float* Gred = (float*)(lds + OFF_GRED);
  float* Gsum = (float*)(lds + OFF_GSUM);
  float* Gs1p = (float*)(lds + OFF_GS1P);
  float* c0l  = (float*)(lds + OFF_C0);
  float* c1l  = (float*)(lds + OFF_C1);
  float* smw  = (float*)(lds + OFF_APOOL);
  float* red  = smw + 256;
  float* shC  = smw + 320;

  const int blk = blockIdx.x, tid = threadIdx.x;
  const int j = blk;                       // owns h-columns [4j, 4j+4)

  unsigned short* inp = (unsigned short*)ws;        // 2 x [32][XSTR] bf16
  unsigned short* h1b = inp + 2*BBAT*XSTR;          // [32][1024] bf16
  float* h1f = (float*)((char*)ws + 275456);        // [32][1024] f32
  float* esc = (float*)((char*)ws + 406528);        // [32][200] f32

  // ---- prologue: weights -> LDS bf16; zero states; esc precompute ----
  for (int i = tid; i < 16*XSTR; i += NTHR) {
    int r = i / XSTR, k = i - r*XSTR;
    int n = (r & 3)*HH + 4*j + (r >> 2);
    float v = 0.f;
    if (k < IN0) v = Wih0[(size_t)n*IN0 + k];
    else if (k < KT) v = Whh0[(size_t)n*HH + (k - IN0)];
    W0[i] = f2bf(v);
  }
  for (int i = tid; i < 16*W1STR; i += NTHR) {
    int r = i / W1STR, k = i - r*W1STR;
    int n = (r & 3)*HH + 4*j + (r >> 2);
    W1I[i] = (k < HH) ? f2bf(Wih1[(size_t)n*HH + k]) : (unsigned short)0;
    W1H[i] = (k < HH) ? f2bf(Whh1[(size_t)n*HH + k]) : (unsigned short)0;
  }
  if (tid < 128) { c0l[tid] = 0.f; c1l[tid] = 0.f; }
  for (int i = blk*NTHR + tid; i < 2*BBAT*XSTR; i += NBLK*NTHR) inp[i] = 0;
  for (int i = blk*NTHR + tid; i < BBAT*HH; i += NBLK*NTHR) { h1b[i] = 0; h1f[i] = 0.f; }
  for (int row = blk; row < BBAT*SE; row += NBLK) {
    float pp = tanhf(enc[(size_t)row*EE + tid]) * Wa[HH + tid];   // EE == NTHR
    pp = bsum(pp, red);
    if (tid == 0) esc[row] = pp;
  }
  grid.sync();

  int cur = 0;
  for (int t = 0; t < TT; ++t) {
    unsigned short* inpA = inp + cur*BBAT*XSTR;
    unsigned short* inpN = inp + (cur^1)*BBAT*XSTR;

    // ===== Phase A: Whh1@h1 partial (MFMA) + attention->ctx + FC pred(t-1) =====
    gemm_mfma<32>(W1H, W1STR, h1b, HH, Gred, Gs1p);
    {
      const int b = blk & 31, esl = blk >> 5;
      if (t > 0) {
        float pp = 0.f;
        for (int i2 = tid; i2 < HH; i2 += NTHR) pp += tanhf(h1f[b*HH + i2]) * Wa[i2];
        float sdot = bsum(pp, red) + ba[0];
        float sc = (tid < SE) ? esc[b*SE + tid] + sdot : -3.4e38f;
        float mx = bmax(sc, red);
        float ex = (tid < SE) ? expf(sc - mx) : 0.f;
        float den = bsum(ex, red);
        if (tid < SE) smw[tid] = ex / den;
      } else {
        if (tid < SE) smw[tid] = 1.0f / (float)SE;
      }
      __syncthreads();
      const int sg = tid >> 6, el = tid & 63;
      const int e = esl*64 + el;
      float a = 0.f;
      for (int s2 = sg*25; s2 < sg*25 + 25; ++s2)
        a = fmaf(smw[s2], enc[((size_t)b*SE + s2)*EE + e], a);
      shC[sg*64 + el] = a;
      __syncthreads();
      if (tid < 64) {
        float r8 = 0.f;
        #pragma unroll
        for (int s3 = 0; s3 < 8; ++s3) r8 += shC[s3*64 + tid];
        inpA[(size_t)b*XSTR + MM + esl*64 + tid] = f2bf(r8);
      }
      if (esl == 0 && tid < MM)
        inpA[(size_t)b*XSTR + tid] = f2bf(audio[((size_t)b*TT + t)*MM + tid]);
    }
    if (t > 0) {   // FC pred(t-1): 10 (b,m) pairs per block, fp32
      const int w = tid >> 6, lane = tid & 63;
      for (int u = w; u < 10; u += 8) {
        int idx = j*10 + u;
        int b = idx / MM, m = idx - b*MM;
        float pp = 0.f;
        #pragma unroll
        for (int cq = 0; cq < 4; ++cq) {
          float4 hv = *(const float4*)(h1f + (size_t)b*HH + cq*256 + lane*4);
          float4 wv = *(const float4*)(Wfc + (size_t)m*HH + cq*256 + lane*4);
          pp = fmaf(hv.x,wv.x, fmaf(hv.y,wv.y, fmaf(hv.z,wv.z, fmaf(hv.w,wv.w, pp))));
        }
        #pragma unroll
        for (int o2 = 32; o2; o2 >>= 1) pp += __shfl_down(pp, o2);
        if (lane == 0) out[((size_t)b*TT + (t-1))*MM + m] = pp + bfc[m];
      }
    }
    grid.sync();

    // ===== Phase B: LSTM0 (K=1632 incl. zero pad) =====
    gemm_mfma<51>(W0, XSTR, inpA, XSTR, Gred, Gsum);
    __syncthreads();
    if (tid < 128) {
      const int b = tid & 31, p = tid >> 5;
      const int o = (b << 4) + (p << 2);
      f32x4 gv = *(const f32x4*)(Gsum + o);
      const int nb = 4*j + p;
      float gi = gv[0] + bih0[nb]        + bhh0[nb];
      float gf = gv[1] + bih0[HH + nb]   + bhh0[HH + nb];
      float gg = gv[2] + bih0[2*HH + nb] + bhh0[2*HH + nb];
      float go = gv[3] + bih0[3*HH + nb] + bhh0[3*HH + nb];
      float cn = sigmf(gf) * c0l[p*32 + b] + sigmf(gi) * tanhf(gg);
      c0l[p*32 + b] = cn;
      inpN[(size_t)b*XSTR + IN0 + nb] = f2bf(sigmf(go) * tanhf(cn));
    }
    grid.sync();

    // ===== Phase C: LSTM1 (Wih1@h0' + Whh1 partial) =====
    gemm_mfma<32>(W1I, W1STR, inpN + IN0, XSTR, Gred, Gsum);
    __syncthreads();
    if (tid < 128) {
      const int b = tid & 31, p = tid >> 5;
      const int o = (b << 4) + (p << 2);
      f32x4 gv = *(const f32x4*)(Gsum + o);
      f32x4 g1 = *(const f32x4*)(Gs1p + o);
      const int nb = 4*j + p;
      float gi = gv[0] + g1[0] + bih1[nb]        + bhh1[nb];
      float gf = gv[1] + g1[1] + bih1[HH + nb]   + bhh1[HH + nb];
      float gg = gv[2] + g1[2] + bih1[2*HH + nb] + bhh1[2*HH + nb];
      float go = gv[3] + g1[3] + bih1[3*HH + nb] + bhh1[3*HH + nb];
      float cn = sigmf(gf) * c1l[p*32 + b] + sigmf(gi) * tanhf(gg);
      c1l[p*32 + b] = cn;
      float hn = sigmf(go) * tanhf(cn);
      h1b[(size_t)b*HH + nb] = f2bf(hn);
      h1f[(size_t)b*HH + nb] = hn;
    }
    grid.sync();
    cur ^= 1;
  }

  // ---- epilogue: FC pred for t = TT-1 ----
  {
    const int w = tid >> 6, lane = tid & 63;
    for (int u = w; u < 10; u += 8) {
      int idx = j*10 + u;
      int b = idx / MM, m = idx - b*MM;
      float pp = 0.f;
      #pragma unroll
      for (int cq = 0; cq < 4; ++cq) {
        float4 hv = *(const float4*)(h1f + (size_t)b*HH + cq*256 + lane*4);
        float4 wv = *(const float4*)(Wfc + (size_t)m*HH + cq*256 + lane*4);
        pp = fmaf(hv.x,wv.x, fmaf(hv.y,wv.y, fmaf(hv.z,wv.z, fmaf(hv.w,wv.w, pp))));
      }
      #pragma unroll
      for (int o2 = 32; o2; o2 >>= 1) pp += __shfl_down(pp, o2);
      if (lane == 0) out[((size_t)b*TT + (TT-1))*MM + m] = pp + bfc[m];
    }
  }
}

extern "C" void kernel_launch(void* const* d_in, const int* in_sizes, int n_in,
                              void* d_out, int out_size, void* d_ws, size_t ws_size,
                              hipStream_t stream) {
  const float* enc  = (const float*)d_in[0];
  const float* audio= (const float*)d_in[1];
  const float* Wih0 = (const float*)d_in[2];
  const float* Whh0 = (const float*)d_in[3];
  const float* bih0 = (const float*)d_in[4];
  const float* bhh0 = (const float*)d_in[5];
  const float* Wih1 = (const float*)d_in[6];
  const float* Whh1 = (const float*)d_in[7];
  const float* bih1 = (const float*)d_in[8];
  const float* bhh1 = (const float*)d_in[9];
  const float* Wa   = (const float*)d_in[10];
  const float* ba   = (const float*)d_in[11];
  const float* Wfc  = (const float*)d_in[12];
  const float* bfc  = (const float*)d_in[13];
  float* out = (float*)d_out;
  float* ws  = (float*)d_ws;

  (void)hipFuncSetAttribute((const void*)decoder_kernel,
                            hipFuncAttributeMaxDynamicSharedMemorySize, LDS_TOTAL);

  void* args[] = { &enc,&audio,&Wih0,&Whh0,&bih0,&bhh0,&Wih1,&Whh1,&bih1,&bhh1,
                   &Wa,&ba,&Wfc,&bfc,&out,&ws };
  hipLaunchCooperativeKernel((const void*)decoder_kernel, dim3(NBLK), dim3(NTHR),
                             args, LDS_TOTAL, stream);
}